// Round 2
// 59275.275 us; speedup vs baseline: 1.0017x; 1.0017x over previous
//
#include <hip/hip_runtime.h>
#include <hip/hip_cooperative_groups.h>

namespace cg = cooperative_groups;

// Problem constants
constexpr int M_ = 16, T_ = 512, D_ = 512, H_ = 512, QK_ = 256, G4_ = 2048;
constexpr float SCALE_ = 1.0f / 16.0f;   // 1/sqrt(QK)

// ---- workspace layout (float element offsets) ----  total ~25.3 MB
// IDENTICAL to the proven-passing layout. Do not grow without ws_size check.
constexpr size_t KEY_OFF = 0;                   // key_x_all  [M][T][QK] f32 (8MB)
constexpr size_t VAL_OFF = 2097152;             // val1_all   [M][T][D]  f32 (16MB)
constexpr size_t H_OFF   = 6291456;             // h          [M][H]
constexpr size_t C_OFF   = H_OFF + 8192;        // c
constexpr size_t TH_OFF  = C_OFF + 8192;        // temp_h (active rows)
constexpr size_t K2_OFF  = TH_OFF + 8192;       // k2 cache [M][H]
constexpr size_t V2_OFF  = K2_OFF + 8192;       // v2 cache
constexpr size_t Q2_OFF  = V2_OFF + 8192;       // q2 per slot [4][H]
constexpr size_t L0_OFF  = Q2_OFF + 2048;       // logit0 partials [M][16]
constexpr size_t L1_OFF  = L0_OFF + 256;        // logit1 partials [M][16]

__device__ inline void load8f(const float* p, float f[8]) {
  float4 a = reinterpret_cast<const float4*>(p)[0];
  float4 b = reinterpret_cast<const float4*>(p)[1];
  f[0] = a.x; f[1] = a.y; f[2] = a.z; f[3] = a.w;
  f[4] = b.x; f[5] = b.y; f[6] = b.z; f[7] = b.w;
}

__device__ inline float waveReduce(float v) {
#pragma unroll
  for (int d = 32; d > 0; d >>= 1) v += __shfl_xor(v, d);
  return v;
}

__device__ inline float sigm(float x) { return 1.f / (1.f + expf(-x)); }

// ============================================================================
// Precompute: key_x_all = x @ Wk^T + bk ; val1_all = x @ Wv^T + bv
// ============================================================================
__global__ void __launch_bounds__(256) keyval_kernel(
    const float* __restrict__ x, const float* __restrict__ Wk,
    const float* __restrict__ Wv, const float* __restrict__ bk,
    const float* __restrict__ bv, float* __restrict__ wsf) {
  __shared__ float Xs[64][33];
  __shared__ float Ws[64][33];
  int bid = blockIdx.x, tid = threadIdx.x;
  int m = bid / 96, r = bid % 96;
  int tt = r / 12, ot = r % 12;
  const float* xb = x + ((size_t)m * T_ + tt * 64) * D_;
  const float* wb; const float* bias; float* dst; int ld;
  if (ot < 4) {
    wb = Wk + (size_t)m * QK_ * D_ + (size_t)(ot * 64) * D_;
    bias = bk + m * QK_ + ot * 64;
    dst = wsf + KEY_OFF + ((size_t)m * T_ + tt * 64) * QK_ + ot * 64;
    ld = QK_;
  } else {
    wb = Wv + (size_t)m * D_ * D_ + (size_t)((ot - 4) * 64) * D_;
    bias = bv + m * D_ + (ot - 4) * 64;
    dst = wsf + VAL_OFF + ((size_t)m * T_ + tt * 64) * D_ + (ot - 4) * 64;
    ld = D_;
  }
  int lr = tid >> 2, lc = (tid & 3) * 8;
  int tx = tid & 15, ty = tid >> 4;
  float acc[4][4] = {};
  for (int k0 = 0; k0 < D_; k0 += 32) {
    float tmp[8];
    load8f(xb + (size_t)lr * D_ + k0 + lc, tmp);
#pragma unroll
    for (int i = 0; i < 8; ++i) Xs[lr][lc + i] = tmp[i];
    load8f(wb + (size_t)lr * D_ + k0 + lc, tmp);
#pragma unroll
    for (int i = 0; i < 8; ++i) Ws[lr][lc + i] = tmp[i];
    __syncthreads();
#pragma unroll
    for (int kk = 0; kk < 32; ++kk) {
      float xa[4], wv4[4];
#pragma unroll
      for (int a = 0; a < 4; ++a) xa[a] = Xs[ty * 4 + a][kk];
#pragma unroll
      for (int b = 0; b < 4; ++b) wv4[b] = Ws[tx * 4 + b][kk];
#pragma unroll
      for (int a = 0; a < 4; ++a)
#pragma unroll
        for (int b = 0; b < 4; ++b) acc[a][b] += xa[a] * wv4[b];
    }
    __syncthreads();
  }
#pragma unroll
  for (int b = 0; b < 4; ++b) {
    float bias_v = bias[tx * 4 + b];
#pragma unroll
    for (int a = 0; a < 4; ++a)
      dst[(size_t)(ty * 4 + a) * ld + tx * 4 + b] = acc[a][b] + bias_v;
  }
}

// ============================================================================
// Main sequential kernel. 256 WGs x 1024 threads. WG = (row m = wg>>4, g = wg&15).
// Persistent VGPR weights per thread: Wq slice (8), Wkg slice (16), Wvg slice (16)
// -> A1 and phase D need no weight traffic; C1 streams Wih+Whh for active rows.
// ============================================================================
__global__ void __launch_bounds__(1024, 4) rim_main(
    const float* __restrict__ Wq, const float* __restrict__ bq,
    const float* __restrict__ bk, const float* __restrict__ bv,
    const float* __restrict__ Wih, const float* __restrict__ bih,
    const float* __restrict__ Whh, const float* __restrict__ bhh,
    const float* __restrict__ Wqg, const float* __restrict__ Wkg,
    const float* __restrict__ Wvg,
    float* __restrict__ wsf, float* __restrict__ out0, float* __restrict__ out1) {
  cg::grid_group grid = cg::this_grid();
  const int wg = blockIdx.x, tid = threadIdx.x;
  const int lane = tid & 63, wv = tid >> 6;
  const int m = wg >> 4, g = wg & 15;
  const int h32 = tid >> 5, oi = tid & 31;

  float* keyA = wsf + KEY_OFF;
  float* valA = wsf + VAL_OFF;
  float* hB  = wsf + H_OFF;
  float* cB  = wsf + C_OFF;
  float* thB = wsf + TH_OFF;
  float* k2B = wsf + K2_OFF;
  float* v2B = wsf + V2_OFF;
  float* q2B = wsf + Q2_OFF;
  float* l0B = wsf + L0_OFF;
  float* l1B = wsf + L1_OFF;

  __shared__ float s_newh[4][512];   // 8 KB
  __shared__ float s_dv[512];        // 2 KB
  __shared__ float s_pdk[16][32];    // 2 KB
  __shared__ float s_pdv[16][32];    // 2 KB
  __shared__ float s_pdq[16][32];    // 2 KB
  __shared__ float s_small[64];
  __shared__ float s_w2[64];
  __shared__ float s_redA[16];
  __shared__ float s_redB[16];
  __shared__ float s_gv[4][8];

  // ---- persistent register weights (survive grid.sync; loaded once) ----
  float wqr[8], wkr[16], wvr[16];
  load8f(Wq + ((size_t)m * QK_ + g * 16 + wv) * H_ + lane * 8, wqr);
  {
    const size_t wo = ((size_t)m * H_ + h32 * 16) * H_ + g * 32 + oi;
#pragma unroll
    for (int i = 0; i < 16; ++i) wkr[i] = Wkg[wo + (size_t)i * H_];
#pragma unroll
    for (int i = 0; i < 16; ++i) wvr[i] = Wvg[wo + (size_t)i * H_];
  }
  const float qb = bq[m * QK_ + g * 16 + wv];
  const float kb = bk[m * QK_ + g * 16 + wv];

  // ws is poisoned each call: zero-init state
  if (g == 0 && tid < 512) {
    hB[m * 512 + tid] = 0.f;
    cB[m * 512 + tid] = 0.f;
  }
  grid.sync();

  int p0 = 0, p1 = 0, p2 = 0, p3 = 0;  // active rows of step t-1
  int r0 = 0, r1 = 0, r2 = 0, r3 = 0;  // active rows of step t

  for (int t = 0; t <= T_; ++t) {
    int slot = -1;
    // ================= Phase A: epilogue of step t-1 =================
    // Only WGs of prev-active rows compute the 16x16 attention; others skip.
    if (t > 0) {
      slot = (m == p0) ? 0 : (m == p1) ? 1 : (m == p2) ? 2 : (m == p3) ? 3 : -1;
      if (slot >= 0) {
        if (tid < 512) {  // scores q2·k2
          int pr = tid >> 3, part = tid & 7;
          int s_ = pr >> 4, j_ = pr & 15;
          const float4* q4 = reinterpret_cast<const float4*>(q2B + s_ * 512 + part * 64);
          const float4* k4 = reinterpret_cast<const float4*>(k2B + j_ * 512 + part * 64);
          float acc = 0.f;
#pragma unroll
          for (int i = 0; i < 16; ++i) {
            float4 a = q4[i], b = k4[i];
            acc += a.x * b.x + a.y * b.y + a.z * b.z + a.w * b.w;
          }
          acc += __shfl_xor(acc, 1);
          acc += __shfl_xor(acc, 2);
          acc += __shfl_xor(acc, 4);
          if (part == 0) s_small[pr] = acc;
        }
        __syncthreads();
        if (tid < 4) {  // row softmax (max-subtract)
          float mx = -1e30f;
          for (int j = 0; j < 16; ++j) mx = fmaxf(mx, s_small[tid * 16 + j]);
          float sm = 0.f;
          for (int j = 0; j < 16; ++j) {
            float e = expf(s_small[tid * 16 + j] - mx);
            s_w2[tid * 16 + j] = e; sm += e;
          }
          float inv = 1.f / sm;
          for (int j = 0; j < 16; ++j) s_w2[tid * 16 + j] *= inv;
        }
        __syncthreads();
        {  // inter + new_h
          int s_ = tid >> 8, o0 = (tid & 255) * 2;
          float ax = 0.f, ay = 0.f;
#pragma unroll
          for (int j = 0; j < 16; ++j) {
            float w = s_w2[s_ * 16 + j];
            float2 v = *reinterpret_cast<const float2*>(v2B + j * 512 + o0);
            ax += w * v.x; ay += w * v.y;
          }
          int myrow = s_ == 0 ? p0 : s_ == 1 ? p1 : s_ == 2 ? p2 : p3;
          const float2 th = *reinterpret_cast<const float2*>(thB + (size_t)myrow * 512 + o0);
          s_newh[s_][o0] = ax + th.x;
          s_newh[s_][o0 + 1] = ay + th.y;
        }
        __syncthreads();
      }
      if (g == 0 && tid < 512) {  // out[t-1] all rows; h update prev-active
        float v = (slot >= 0) ? s_newh[slot][tid] : hB[m * 512 + tid];
        out0[(size_t)(t - 1) * (M_ * H_) + m * 512 + tid] = v;
        if (slot >= 0) hB[m * 512 + tid] = v;
      }
    }
    if (t == T_) break;

    // --- A1: q = h@Wq^T + bq (register weights), logit partials ---
    {
      float kv = keyA[((size_t)m * T_ + t) * QK_ + g * 16 + wv];  // issue early
      float hreg[8];
      if (slot >= 0) {
#pragma unroll
        for (int i = 0; i < 8; ++i) hreg[i] = s_newh[slot][lane * 8 + i];
      } else {
        load8f(hB + m * 512 + lane * 8, hreg);
      }
      float acc = 0.f;
#pragma unroll
      for (int i = 0; i < 8; ++i) acc += hreg[i] * wqr[i];
      acc = waveReduce(acc);
      if (lane == 0) {
        float q = acc + qb;
        s_redA[wv] = q * kv;
        s_redB[wv] = q * kb;
      }
      __syncthreads();
      if (tid == 0) {  // deterministic fixed-order partial
        float a = 0.f, b = 0.f;
        for (int w = 0; w < 16; ++w) { a += s_redA[w]; b += s_redB[w]; }
        l1B[m * 16 + g] = a;
        l0B[m * 16 + g] = b;
      }
    }
    grid.sync();

    // ================= Phase C =================
    if (tid < 16) {
      float l0 = 0.f, l1 = 0.f;
      for (int i = 0; i < 16; ++i) { l0 += l0B[tid * 16 + i]; l1 += l1B[tid * 16 + i]; }
      l0 *= SCALE_; l1 *= SCALE_;
      float mx = fmaxf(l0, l1);
      float e0 = expf(l0 - mx), e1 = expf(l1 - mx);
      float inv = 1.f / (e0 + e1);
      s_small[tid] = e0 * inv;        // att0
      s_small[16 + tid] = e1 * inv;   // att1
    }
    __syncthreads();
    {  // top_k(-att0, 4): 4 smallest att0, ties -> smaller index
      unsigned chosen = 0;
      int rr[4];
#pragma unroll
      for (int s = 0; s < 4; ++s) {
        float best = -2.f; int bm = 0;
        for (int mm = 0; mm < 16; ++mm) {
          if (chosen & (1u << mm)) continue;
          float v = -s_small[mm];
          if (v > best) { best = v; bm = mm; }
        }
        rr[s] = bm; chosen |= 1u << bm;
      }
      r0 = rr[0]; r1 = rr[1]; r2 = rr[2]; r3 = rr[3];
    }
    if (wg == 0 && tid < 4) {
      int rowv = tid == 0 ? r0 : tid == 1 ? r1 : tid == 2 ? r2 : r3;
      out1[(size_t)t * 4 + tid] = (float)rowv;
    }
    // --- C1: gates + LSTM cell. WG=(slot, j-chunk of 8); wave = 2 gates. ---
    // Direct per-wave global loads for bv/val1/h (L1-broadcast), no LDS stage.
    {
      int slot_c = wg >> 6, jc = wg & 63, j0 = jc * 8;
      int mA = slot_c == 0 ? r0 : slot_c == 1 ? r1 : slot_c == 2 ? r2 : r3;
      float a0v = s_small[mA], a1v = s_small[16 + mA];
      float bvr[8], vlr[8], hr[8];
      load8f(bv + mA * D_ + lane * 8, bvr);
      load8f(valA + ((size_t)mA * T_ + t) * D_ + lane * 8, vlr);
      load8f(hB + mA * 512 + lane * 8, hr);
      float selr[8];
#pragma unroll
      for (int i = 0; i < 8; ++i) selr[i] = a0v * bvr[i] + a1v * vlr[i];
#pragma unroll
      for (int u = 0; u < 2; ++u) {
        int gl = wv * 2 + u;            // 0..31
        int type = gl >> 3, jj = gl & 7;
        int gidx = type * 512 + j0 + jj;
        float wi[8], wh[8];
        load8f(Wih + ((size_t)mA * G4_ + gidx) * D_ + lane * 8, wi);
        load8f(Whh + ((size_t)mA * G4_ + gidx) * H_ + lane * 8, wh);
        float acc = 0.f;
#pragma unroll
        for (int k = 0; k < 8; ++k) acc += selr[k] * wi[k] + hr[k] * wh[k];
        acc = waveReduce(acc);
        if (lane == 0)
          s_gv[type][jj] = acc + bih[mA * G4_ + gidx] + bhh[mA * G4_ + gidx];
      }
      __syncthreads();
      if (tid < 8) {
        float gi = s_gv[0][tid], gf = s_gv[1][tid], gg = s_gv[2][tid], go = s_gv[3][tid];
        int j = j0 + tid;
        float cold = cB[mA * 512 + j];
        float cn = sigm(gf) * cold + sigm(gi) * tanhf(gg);
        float hn = sigm(go) * tanhf(cn);
        cB[mA * 512 + j] = cn;     // new_c (active rows)
        thB[mA * 512 + j] = hn;    // temp_h (active rows)
      }
    }
    grid.sync();

    // ================= Phase D: k2/v2 (+q2) from persistent registers ======
    // Row m's 16 WGs own o-slices of 32. Skip rows whose source h is unchanged.
    {
      unsigned amask = (1u << r0) | (1u << r1) | (1u << r2) | (1u << r3);
      unsigned pmask = (1u << p0) | (1u << p1) | (1u << p2) | (1u << p3);
      bool act = (amask >> m) & 1;
      bool prevact = (t > 0) && ((pmask >> m) & 1);
      bool dirty = act || prevact || (t == 0);
      if (dirty) {
        const float* src = act ? thB + m * 512 : hB + m * 512;
        if (tid < 512) s_dv[tid] = src[tid];
        float wq2[16];
        int qslot = -1;
        if (act) {  // stream Wqg slice for active rows (4 MB/step total)
          qslot = (m == r0) ? 0 : (m == r1) ? 1 : (m == r2) ? 2 : 3;
          const size_t wo = ((size_t)m * H_ + h32 * 16) * H_ + g * 32 + oi;
#pragma unroll
          for (int i = 0; i < 16; ++i) wq2[i] = Wqg[wo + (size_t)i * H_];
        }
        __syncthreads();
        float pk = 0.f, pv = 0.f, pq = 0.f;
#pragma unroll
        for (int i = 0; i < 16; ++i) {
          float s = s_dv[h32 * 16 + i];
          pk += s * wkr[i];
          pv += s * wvr[i];
        }
        if (act) {
#pragma unroll
          for (int i = 0; i < 16; ++i) pq += s_dv[h32 * 16 + i] * wq2[i];
        }
        pk += __shfl_xor(pk, 32);
        pv += __shfl_xor(pv, 32);
        pq += __shfl_xor(pq, 32);
        if (lane < 32) {
          s_pdk[wv][lane] = pk;
          s_pdv[wv][lane] = pv;
          s_pdq[wv][lane] = pq;
        }
        __syncthreads();
        if (tid < 32) {
          float a = 0.f, b = 0.f, c = 0.f;
          for (int w = 0; w < 16; ++w) {  // fixed order
            a += s_pdk[w][tid]; b += s_pdv[w][tid]; c += s_pdq[w][tid];
          }
          k2B[m * 512 + g * 32 + tid] = a;
          v2B[m * 512 + g * 32 + tid] = b;
          if (act) q2B[qslot * 512 + g * 32 + tid] = c;
        }
      }
      // new_c = m*c_new: zero c when a row just went inactive
      if (!act && prevact && g == 0 && tid < 512) cB[m * 512 + tid] = 0.f;
    }
    p0 = r0; p1 = r1; p2 = r2; p3 = r3;
    grid.sync();
  }
}

// ============================================================================
extern "C" void kernel_launch(void* const* d_in, const int* in_sizes, int n_in,
                              void* d_out, int out_size, void* d_ws, size_t ws_size,
                              hipStream_t stream) {
  const float* x   = (const float*)d_in[0];
  const float* Wq  = (const float*)d_in[1];
  const float* bq  = (const float*)d_in[2];
  const float* Wk  = (const float*)d_in[3];
  const float* bk  = (const float*)d_in[4];
  const float* Wv  = (const float*)d_in[5];
  const float* bv  = (const float*)d_in[6];
  const float* Wih = (const float*)d_in[7];
  const float* bih = (const float*)d_in[8];
  const float* Whh = (const float*)d_in[9];
  const float* bhh = (const float*)d_in[10];
  const float* Wqg = (const float*)d_in[11];
  const float* Wkg = (const float*)d_in[12];
  const float* Wvg = (const float*)d_in[13];
  float* wsf = (float*)d_ws;
  float* out0 = (float*)d_out;
  float* out1 = out0 + (size_t)T_ * M_ * H_;
  (void)in_sizes; (void)n_in; (void)out_size; (void)ws_size;

  hipLaunchKernelGGL(keyval_kernel, dim3(1536), dim3(256), 0, stream,
                     x, Wk, Wv, bk, bv, wsf);

  void* kargs[] = {(void*)&Wq, (void*)&bq, (void*)&bk, (void*)&bv,
                   (void*)&Wih, (void*)&bih, (void*)&Whh, (void*)&bhh,
                   (void*)&Wqg, (void*)&Wkg, (void*)&Wvg,
                   (void*)&wsf, (void*)&out0, (void*)&out1};
  hipLaunchCooperativeKernel((void*)rim_main, dim3(256), dim3(1024), kargs, 0,
                             stream);
}

// Round 3
// 35687.509 us; speedup vs baseline: 1.6638x; 1.6610x over previous
//
#include <hip/hip_runtime.h>

// Problem constants
constexpr int M_ = 16, T_ = 512, D_ = 512, H_ = 512, QK_ = 256, G4_ = 2048;
constexpr float SCALE_ = 1.0f / 16.0f;   // 1/sqrt(QK)

// ---- workspace layout (float element offsets) ----  total ~25.3 MB + 2.2KB
constexpr size_t KEY_OFF = 0;                   // key_x_all  [M][T][QK] f32 (8MB)
constexpr size_t VAL_OFF = 2097152;             // val1_all   [M][T][D]  f32 (16MB)
constexpr size_t H_OFF   = 6291456;             // h          [M][H]
constexpr size_t C_OFF   = H_OFF + 8192;        // c
constexpr size_t TH_OFF  = C_OFF + 8192;        // temp_h (active rows)
constexpr size_t K2_OFF  = TH_OFF + 8192;       // k2 cache [M][H]
constexpr size_t V2_OFF  = K2_OFF + 8192;       // v2 cache
constexpr size_t Q2_OFF  = V2_OFF + 8192;       // q2 per slot [4][H]
constexpr size_t L0_OFF  = Q2_OFF + 2048;       // logit0 partials [M][16]
constexpr size_t L1_OFF  = L0_OFF + 256;        // logit1 partials [M][16]
constexpr size_t BAR_OFF = L1_OFF + 256;        // barrier: 16 sub cnts (stride 32) + root
constexpr int    BAR_WORDS = 16 * 32 + 32;      // 544 words

__device__ inline void load8f(const float* p, float f[8]) {
  float4 a = reinterpret_cast<const float4*>(p)[0];
  float4 b = reinterpret_cast<const float4*>(p)[1];
  f[0] = a.x; f[1] = a.y; f[2] = a.z; f[3] = a.w;
  f[4] = b.x; f[5] = b.y; f[6] = b.z; f[7] = b.w;
}

__device__ inline float waveReduce(float v) {
#pragma unroll
  for (int d = 32; d > 0; d >>= 1) v += __shfl_xor(v, d);
  return v;
}

__device__ inline float sigm(float x) { return 1.f / (1.f + expf(-x)); }

// ---------------------------------------------------------------------------
// Hierarchical monotone grid barrier (256 WGs = 16 groups x 16).
// Counters never reset -> no reset races. idx is the 1-based barrier number,
// identical across all WGs (uniform control flow).
// ---------------------------------------------------------------------------
__device__ __forceinline__ void gbar(float* wsf, unsigned idx) {
  unsigned* bar = reinterpret_cast<unsigned*>(wsf + BAR_OFF);
  __syncthreads();                 // all WG stores drained (vmcnt) before fence
  if (threadIdx.x == 0) {
    __threadfence();               // release: L2 writeback, writes visible device-wide
    const int sub = blockIdx.x >> 4;
    unsigned a = __hip_atomic_fetch_add(&bar[sub * 32], 1u, __ATOMIC_RELAXED,
                                        __HIP_MEMORY_SCOPE_AGENT);
    if (a == idx * 16u - 1u)       // last of my 16-WG group for this barrier
      __hip_atomic_fetch_add(&bar[512], 1u, __ATOMIC_RELAXED,
                             __HIP_MEMORY_SCOPE_AGENT);
    while (__hip_atomic_load(&bar[512], __ATOMIC_RELAXED,
                             __HIP_MEMORY_SCOPE_AGENT) < idx * 16u)
      __builtin_amdgcn_s_sleep(2);
    __threadfence();               // acquire: invalidate L1/L2 before reads
  }
  __syncthreads();
}

// ============================================================================
// Precompute: key_x_all = x @ Wk^T + bk ; val1_all = x @ Wv^T + bv
// Block 0 additionally zeroes the barrier counters (ws is poisoned).
// ============================================================================
__global__ void __launch_bounds__(256) keyval_kernel(
    const float* __restrict__ x, const float* __restrict__ Wk,
    const float* __restrict__ Wv, const float* __restrict__ bk,
    const float* __restrict__ bv, float* __restrict__ wsf) {
  __shared__ float Xs[64][33];
  __shared__ float Ws[64][33];
  int bid = blockIdx.x, tid = threadIdx.x;
  if (bid == 0) {
    for (int i = tid; i < BAR_WORDS; i += 256)
      reinterpret_cast<unsigned*>(wsf + BAR_OFF)[i] = 0u;
  }
  int m = bid / 96, r = bid % 96;
  int tt = r / 12, ot = r % 12;
  const float* xb = x + ((size_t)m * T_ + tt * 64) * D_;
  const float* wb; const float* bias; float* dst; int ld;
  if (ot < 4) {
    wb = Wk + (size_t)m * QK_ * D_ + (size_t)(ot * 64) * D_;
    bias = bk + m * QK_ + ot * 64;
    dst = wsf + KEY_OFF + ((size_t)m * T_ + tt * 64) * QK_ + ot * 64;
    ld = QK_;
  } else {
    wb = Wv + (size_t)m * D_ * D_ + (size_t)((ot - 4) * 64) * D_;
    bias = bv + m * D_ + (ot - 4) * 64;
    dst = wsf + VAL_OFF + ((size_t)m * T_ + tt * 64) * D_ + (ot - 4) * 64;
    ld = D_;
  }
  int lr = tid >> 2, lc = (tid & 3) * 8;
  int tx = tid & 15, ty = tid >> 4;
  float acc[4][4] = {};
  for (int k0 = 0; k0 < D_; k0 += 32) {
    float tmp[8];
    load8f(xb + (size_t)lr * D_ + k0 + lc, tmp);
#pragma unroll
    for (int i = 0; i < 8; ++i) Xs[lr][lc + i] = tmp[i];
    load8f(wb + (size_t)lr * D_ + k0 + lc, tmp);
#pragma unroll
    for (int i = 0; i < 8; ++i) Ws[lr][lc + i] = tmp[i];
    __syncthreads();
#pragma unroll
    for (int kk = 0; kk < 32; ++kk) {
      float xa[4], wv4[4];
#pragma unroll
      for (int a = 0; a < 4; ++a) xa[a] = Xs[ty * 4 + a][kk];
#pragma unroll
      for (int b = 0; b < 4; ++b) wv4[b] = Ws[tx * 4 + b][kk];
#pragma unroll
      for (int a = 0; a < 4; ++a)
#pragma unroll
        for (int b = 0; b < 4; ++b) acc[a][b] += xa[a] * wv4[b];
    }
    __syncthreads();
  }
#pragma unroll
  for (int b = 0; b < 4; ++b) {
    float bias_v = bias[tx * 4 + b];
#pragma unroll
    for (int a = 0; a < 4; ++a)
      dst[(size_t)(ty * 4 + a) * ld + tx * 4 + b] = acc[a][b] + bias_v;
  }
}

// ============================================================================
// Main sequential kernel. 256 WGs x 1024 threads. WG = (row m = wg>>4, g = wg&15).
// Persistent VGPR weights per thread: Wq slice (8), Wkg slice (16), Wvg slice (16).
// All grid syncs via custom hierarchical barrier (gbar).
// ============================================================================
__global__ void __launch_bounds__(1024, 4) rim_main(
    const float* __restrict__ Wq, const float* __restrict__ bq,
    const float* __restrict__ bk, const float* __restrict__ bv,
    const float* __restrict__ Wih, const float* __restrict__ bih,
    const float* __restrict__ Whh, const float* __restrict__ bhh,
    const float* __restrict__ Wqg, const float* __restrict__ Wkg,
    const float* __restrict__ Wvg,
    float* __restrict__ wsf, float* __restrict__ out0, float* __restrict__ out1) {
  const int wg = blockIdx.x, tid = threadIdx.x;
  const int lane = tid & 63, wv = tid >> 6;
  const int m = wg >> 4, g = wg & 15;
  const int h32 = tid >> 5, oi = tid & 31;

  float* keyA = wsf + KEY_OFF;
  float* valA = wsf + VAL_OFF;
  float* hB  = wsf + H_OFF;
  float* cB  = wsf + C_OFF;
  float* thB = wsf + TH_OFF;
  float* k2B = wsf + K2_OFF;
  float* v2B = wsf + V2_OFF;
  float* q2B = wsf + Q2_OFF;
  float* l0B = wsf + L0_OFF;
  float* l1B = wsf + L1_OFF;

  __shared__ float s_newh[4][512];   // 8 KB
  __shared__ float s_dv[512];        // 2 KB
  __shared__ float s_pdk[16][32];    // 2 KB
  __shared__ float s_pdv[16][32];    // 2 KB
  __shared__ float s_pdq[16][32];    // 2 KB
  __shared__ float s_small[64];
  __shared__ float s_w2[64];
  __shared__ float s_redA[16];
  __shared__ float s_redB[16];
  __shared__ float s_gv[4][8];

  // ---- persistent register weights (loaded once) ----
  float wqr[8], wkr[16], wvr[16];
  load8f(Wq + ((size_t)m * QK_ + g * 16 + wv) * H_ + lane * 8, wqr);
  {
    const size_t wo = ((size_t)m * H_ + h32 * 16) * H_ + g * 32 + oi;
#pragma unroll
    for (int i = 0; i < 16; ++i) wkr[i] = Wkg[wo + (size_t)i * H_];
#pragma unroll
    for (int i = 0; i < 16; ++i) wvr[i] = Wvg[wo + (size_t)i * H_];
  }
  const float qb = bq[m * QK_ + g * 16 + wv];
  const float kb = bk[m * QK_ + g * 16 + wv];

  unsigned bno = 0;  // barrier index (uniform across grid)

  // ws is poisoned each call: zero-init state
  if (g == 0 && tid < 512) {
    hB[m * 512 + tid] = 0.f;
    cB[m * 512 + tid] = 0.f;
  }
  gbar(wsf, ++bno);

  int p0 = 0, p1 = 0, p2 = 0, p3 = 0;  // active rows of step t-1
  int r0 = 0, r1 = 0, r2 = 0, r3 = 0;  // active rows of step t

  for (int t = 0; t <= T_; ++t) {
    int slot = -1;
    // ================= Phase A: epilogue of step t-1 =================
    if (t > 0) {
      slot = (m == p0) ? 0 : (m == p1) ? 1 : (m == p2) ? 2 : (m == p3) ? 3 : -1;
      if (slot >= 0) {
        if (tid < 512) {  // scores q2·k2
          int pr = tid >> 3, part = tid & 7;
          int s_ = pr >> 4, j_ = pr & 15;
          const float4* q4 = reinterpret_cast<const float4*>(q2B + s_ * 512 + part * 64);
          const float4* k4 = reinterpret_cast<const float4*>(k2B + j_ * 512 + part * 64);
          float acc = 0.f;
#pragma unroll
          for (int i = 0; i < 16; ++i) {
            float4 a = q4[i], b = k4[i];
            acc += a.x * b.x + a.y * b.y + a.z * b.z + a.w * b.w;
          }
          acc += __shfl_xor(acc, 1);
          acc += __shfl_xor(acc, 2);
          acc += __shfl_xor(acc, 4);
          if (part == 0) s_small[pr] = acc;
        }
        __syncthreads();
        if (tid < 4) {  // row softmax (max-subtract)
          float mx = -1e30f;
          for (int j = 0; j < 16; ++j) mx = fmaxf(mx, s_small[tid * 16 + j]);
          float sm = 0.f;
          for (int j = 0; j < 16; ++j) {
            float e = expf(s_small[tid * 16 + j] - mx);
            s_w2[tid * 16 + j] = e; sm += e;
          }
          float inv = 1.f / sm;
          for (int j = 0; j < 16; ++j) s_w2[tid * 16 + j] *= inv;
        }
        __syncthreads();
        {  // inter + new_h
          int s_ = tid >> 8, o0 = (tid & 255) * 2;
          float ax = 0.f, ay = 0.f;
#pragma unroll
          for (int j = 0; j < 16; ++j) {
            float w = s_w2[s_ * 16 + j];
            float2 v = *reinterpret_cast<const float2*>(v2B + j * 512 + o0);
            ax += w * v.x; ay += w * v.y;
          }
          int myrow = s_ == 0 ? p0 : s_ == 1 ? p1 : s_ == 2 ? p2 : p3;
          const float2 th = *reinterpret_cast<const float2*>(thB + (size_t)myrow * 512 + o0);
          s_newh[s_][o0] = ax + th.x;
          s_newh[s_][o0 + 1] = ay + th.y;
        }
        __syncthreads();
      }
      if (g == 0 && tid < 512) {  // out[t-1] all rows; h update prev-active
        float v = (slot >= 0) ? s_newh[slot][tid] : hB[m * 512 + tid];
        out0[(size_t)(t - 1) * (M_ * H_) + m * 512 + tid] = v;
        if (slot >= 0) hB[m * 512 + tid] = v;
      }
    }
    if (t == T_) break;

    // --- A1: q = h@Wq^T + bq (register weights), logit partials ---
    {
      float kv = keyA[((size_t)m * T_ + t) * QK_ + g * 16 + wv];  // issue early
      float hreg[8];
      if (slot >= 0) {
#pragma unroll
        for (int i = 0; i < 8; ++i) hreg[i] = s_newh[slot][lane * 8 + i];
      } else {
        load8f(hB + m * 512 + lane * 8, hreg);
      }
      float acc = 0.f;
#pragma unroll
      for (int i = 0; i < 8; ++i) acc += hreg[i] * wqr[i];
      acc = waveReduce(acc);
      if (lane == 0) {
        float q = acc + qb;
        s_redA[wv] = q * kv;
        s_redB[wv] = q * kb;
      }
      __syncthreads();
      if (tid == 0) {  // deterministic fixed-order partial
        float a = 0.f, b = 0.f;
        for (int w = 0; w < 16; ++w) { a += s_redA[w]; b += s_redB[w]; }
        l1B[m * 16 + g] = a;
        l0B[m * 16 + g] = b;
      }
    }
    gbar(wsf, ++bno);

    // ================= Phase C =================
    if (tid < 16) {
      float l0 = 0.f, l1 = 0.f;
      for (int i = 0; i < 16; ++i) { l0 += l0B[tid * 16 + i]; l1 += l1B[tid * 16 + i]; }
      l0 *= SCALE_; l1 *= SCALE_;
      float mx = fmaxf(l0, l1);
      float e0 = expf(l0 - mx), e1 = expf(l1 - mx);
      float inv = 1.f / (e0 + e1);
      s_small[tid] = e0 * inv;        // att0
      s_small[16 + tid] = e1 * inv;   // att1
    }
    __syncthreads();
    {  // top_k(-att0, 4): 4 smallest att0, ties -> smaller index
      unsigned chosen = 0;
      int rr[4];
#pragma unroll
      for (int s = 0; s < 4; ++s) {
        float best = -2.f; int bm = 0;
        for (int mm = 0; mm < 16; ++mm) {
          if (chosen & (1u << mm)) continue;
          float v = -s_small[mm];
          if (v > best) { best = v; bm = mm; }
        }
        rr[s] = bm; chosen |= 1u << bm;
      }
      r0 = rr[0]; r1 = rr[1]; r2 = rr[2]; r3 = rr[3];
    }
    if (wg == 0 && tid < 4) {
      int rowv = tid == 0 ? r0 : tid == 1 ? r1 : tid == 2 ? r2 : r3;
      out1[(size_t)t * 4 + tid] = (float)rowv;
    }
    // --- C1: gates + LSTM cell. WG=(slot, j-chunk of 8); wave = 2 gates. ---
    {
      int slot_c = wg >> 6, jc = wg & 63, j0 = jc * 8;
      int mA = slot_c == 0 ? r0 : slot_c == 1 ? r1 : slot_c == 2 ? r2 : r3;
      float a0v = s_small[mA], a1v = s_small[16 + mA];
      float bvr[8], vlr[8], hr[8];
      load8f(bv + mA * D_ + lane * 8, bvr);
      load8f(valA + ((size_t)mA * T_ + t) * D_ + lane * 8, vlr);
      load8f(hB + mA * 512 + lane * 8, hr);
      float selr[8];
#pragma unroll
      for (int i = 0; i < 8; ++i) selr[i] = a0v * bvr[i] + a1v * vlr[i];
#pragma unroll
      for (int u = 0; u < 2; ++u) {
        int gl = wv * 2 + u;            // 0..31
        int type = gl >> 3, jj = gl & 7;
        int gidx = type * 512 + j0 + jj;
        float wi[8], wh[8];
        load8f(Wih + ((size_t)mA * G4_ + gidx) * D_ + lane * 8, wi);
        load8f(Whh + ((size_t)mA * G4_ + gidx) * H_ + lane * 8, wh);
        float acc = 0.f;
#pragma unroll
        for (int k = 0; k < 8; ++k) acc += selr[k] * wi[k] + hr[k] * wh[k];
        acc = waveReduce(acc);
        if (lane == 0)
          s_gv[type][jj] = acc + bih[mA * G4_ + gidx] + bhh[mA * G4_ + gidx];
      }
      __syncthreads();
      if (tid < 8) {
        float gi = s_gv[0][tid], gf = s_gv[1][tid], gg = s_gv[2][tid], go = s_gv[3][tid];
        int j = j0 + tid;
        float cold = cB[mA * 512 + j];
        float cn = sigm(gf) * cold + sigm(gi) * tanhf(gg);
        float hn = sigm(go) * tanhf(cn);
        cB[mA * 512 + j] = cn;     // new_c (active rows)
        thB[mA * 512 + j] = hn;    // temp_h (active rows)
      }
    }
    gbar(wsf, ++bno);

    // ================= Phase D: k2/v2 (+q2) from persistent registers ======
    {
      unsigned amask = (1u << r0) | (1u << r1) | (1u << r2) | (1u << r3);
      unsigned pmask = (1u << p0) | (1u << p1) | (1u << p2) | (1u << p3);
      bool act = (amask >> m) & 1;
      bool prevact = (t > 0) && ((pmask >> m) & 1);
      bool dirty = act || prevact || (t == 0);
      if (dirty) {
        const float* src = act ? thB + m * 512 : hB + m * 512;
        if (tid < 512) s_dv[tid] = src[tid];
        float wq2[16];
        int qslot = -1;
        if (act) {  // stream Wqg slice for active rows (4 MB/step total)
          qslot = (m == r0) ? 0 : (m == r1) ? 1 : (m == r2) ? 2 : 3;
          const size_t wo = ((size_t)m * H_ + h32 * 16) * H_ + g * 32 + oi;
#pragma unroll
          for (int i = 0; i < 16; ++i) wq2[i] = Wqg[wo + (size_t)i * H_];
        }
        __syncthreads();
        float pk = 0.f, pv = 0.f, pq = 0.f;
#pragma unroll
        for (int i = 0; i < 16; ++i) {
          float s = s_dv[h32 * 16 + i];
          pk += s * wkr[i];
          pv += s * wvr[i];
        }
        if (act) {
#pragma unroll
          for (int i = 0; i < 16; ++i) pq += s_dv[h32 * 16 + i] * wq2[i];
        }
        pk += __shfl_xor(pk, 32);
        pv += __shfl_xor(pv, 32);
        pq += __shfl_xor(pq, 32);
        if (lane < 32) {
          s_pdk[wv][lane] = pk;
          s_pdv[wv][lane] = pv;
          s_pdq[wv][lane] = pq;
        }
        __syncthreads();
        if (tid < 32) {
          float a = 0.f, b = 0.f, c = 0.f;
          for (int w = 0; w < 16; ++w) {  // fixed order
            a += s_pdk[w][tid]; b += s_pdv[w][tid]; c += s_pdq[w][tid];
          }
          k2B[m * 512 + g * 32 + tid] = a;
          v2B[m * 512 + g * 32 + tid] = b;
          if (act) q2B[qslot * 512 + g * 32 + tid] = c;
        }
      }
      // new_c = m*c_new: zero c when a row just went inactive
      if (!act && prevact && g == 0 && tid < 512) cB[m * 512 + tid] = 0.f;
    }
    p0 = r0; p1 = r1; p2 = r2; p3 = r3;
    gbar(wsf, ++bno);
  }
}

// ============================================================================
extern "C" void kernel_launch(void* const* d_in, const int* in_sizes, int n_in,
                              void* d_out, int out_size, void* d_ws, size_t ws_size,
                              hipStream_t stream) {
  const float* x   = (const float*)d_in[0];
  const float* Wq  = (const float*)d_in[1];
  const float* bq  = (const float*)d_in[2];
  const float* Wk  = (const float*)d_in[3];
  const float* bk  = (const float*)d_in[4];
  const float* Wv  = (const float*)d_in[5];
  const float* bv  = (const float*)d_in[6];
  const float* Wih = (const float*)d_in[7];
  const float* bih = (const float*)d_in[8];
  const float* Whh = (const float*)d_in[9];
  const float* bhh = (const float*)d_in[10];
  const float* Wqg = (const float*)d_in[11];
  const float* Wkg = (const float*)d_in[12];
  const float* Wvg = (const float*)d_in[13];
  float* wsf = (float*)d_ws;
  float* out0 = (float*)d_out;
  float* out1 = out0 + (size_t)T_ * M_ * H_;
  (void)in_sizes; (void)n_in; (void)out_size; (void)ws_size;

  hipLaunchKernelGGL(keyval_kernel, dim3(1536), dim3(256), 0, stream,
                     x, Wk, Wv, bk, bv, wsf);

  void* kargs[] = {(void*)&Wq, (void*)&bq, (void*)&bk, (void*)&bv,
                   (void*)&Wih, (void*)&bih, (void*)&Whh, (void*)&bhh,
                   (void*)&Wqg, (void*)&Wkg, (void*)&Wvg,
                   (void*)&wsf, (void*)&out0, (void*)&out1};
  hipLaunchCooperativeKernel((void*)rim_main, dim3(256), dim3(1024), kargs, 0,
                             stream);
}

// Round 4
// 30269.312 us; speedup vs baseline: 1.9616x; 1.1790x over previous
//
#include <hip/hip_runtime.h>

// Problem constants
constexpr int M_ = 16, T_ = 512, D_ = 512, H_ = 512, QK_ = 256, G4_ = 2048;
constexpr float SCALE_ = 1.0f / 16.0f;   // 1/sqrt(QK)

// ---- workspace layout (float element offsets) ----  total ~25.3 MB + 2.2KB
constexpr size_t KEY_OFF = 0;                   // key_x_all  [M][T][QK] f32 (8MB)
constexpr size_t VAL_OFF = 2097152;             // val1_all   [M][T][D]  f32 (16MB)
constexpr size_t H_OFF   = 6291456;             // h          [M][H]
constexpr size_t C_OFF   = H_OFF + 8192;        // c
constexpr size_t TH_OFF  = C_OFF + 8192;        // temp_h (active rows)
constexpr size_t K2_OFF  = TH_OFF + 8192;       // k2 cache [M][H]
constexpr size_t V2_OFF  = K2_OFF + 8192;       // v2 cache
constexpr size_t Q2_OFF  = V2_OFF + 8192;       // q2 per slot [4][H]
constexpr size_t L0_OFF  = Q2_OFF + 2048;       // logit0 partials [M][16]
constexpr size_t L1_OFF  = L0_OFF + 256;        // logit1 partials [M][16]
constexpr size_t BAR_OFF = L1_OFF + 256;        // barrier: 16 sub cnts (stride 32) + root
constexpr int    BAR_WORDS = 16 * 32 + 32;      // 544 words

__device__ inline void load8f(const float* p, float f[8]) {
  float4 a = reinterpret_cast<const float4*>(p)[0];
  float4 b = reinterpret_cast<const float4*>(p)[1];
  f[0] = a.x; f[1] = a.y; f[2] = a.z; f[3] = a.w;
  f[4] = b.x; f[5] = b.y; f[6] = b.z; f[7] = b.w;
}

// ---- agent-scope (cross-XCD coherent, L2-bypassing) access for MUTABLE
// shared buffers. Immutable data keeps the normal cached path. Using these
// for ALL accesses to h/c/th/k2/v2/q2/l0/l1 means no stale L2 copies can
// ever exist -> no __threadfence (L2 writeback/invalidate) needed anywhere.
__device__ __forceinline__ float ldf(const float* p) {
  return __hip_atomic_load(p, __ATOMIC_RELAXED, __HIP_MEMORY_SCOPE_AGENT);
}
__device__ __forceinline__ void stf(float* p, float v) {
  __hip_atomic_store(p, v, __ATOMIC_RELAXED, __HIP_MEMORY_SCOPE_AGENT);
}
__device__ __forceinline__ float2 ldf2(const float* p) {
  unsigned long long u = __hip_atomic_load(
      reinterpret_cast<const unsigned long long*>(p),
      __ATOMIC_RELAXED, __HIP_MEMORY_SCOPE_AGENT);
  return __builtin_bit_cast(float2, u);
}
__device__ __forceinline__ void ld8f_cg(const float* p, float f[8]) {
  float2 a = ldf2(p), b = ldf2(p + 2), c = ldf2(p + 4), d = ldf2(p + 6);
  f[0] = a.x; f[1] = a.y; f[2] = b.x; f[3] = b.y;
  f[4] = c.x; f[5] = c.y; f[6] = d.x; f[7] = d.y;
}

__device__ inline float waveReduce(float v) {
#pragma unroll
  for (int d = 32; d > 0; d >>= 1) v += __shfl_xor(v, d);
  return v;
}

__device__ inline float sigm(float x) { return 1.f / (1.f + expf(-x)); }

// ---------------------------------------------------------------------------
// Hierarchical monotone grid barrier (256 WGs = 16 groups x 16), FENCE-FREE.
// All mutable shared data uses sc-bypass ops, so visibility only needs each
// wave's own vmcnt drained before arrival. No buffer_wbl2/buffer_inv -> L2
// keeps all immutable data (weights, key/val, biases) across barriers.
// ---------------------------------------------------------------------------
__device__ __forceinline__ void gbar(float* wsf, unsigned idx) {
  unsigned* bar = reinterpret_cast<unsigned*>(wsf + BAR_OFF);
  asm volatile("s_waitcnt vmcnt(0)" ::: "memory");  // each wave drains its stores
  __syncthreads();
  if (threadIdx.x == 0) {
    const int sub = blockIdx.x >> 4;
    unsigned a = __hip_atomic_fetch_add(&bar[sub * 32], 1u, __ATOMIC_RELAXED,
                                        __HIP_MEMORY_SCOPE_AGENT);
    if (a == idx * 16u - 1u)       // last of my 16-WG group for this barrier
      __hip_atomic_fetch_add(&bar[512], 1u, __ATOMIC_RELAXED,
                             __HIP_MEMORY_SCOPE_AGENT);
    while (__hip_atomic_load(&bar[512], __ATOMIC_RELAXED,
                             __HIP_MEMORY_SCOPE_AGENT) < idx * 16u)
      __builtin_amdgcn_s_sleep(1);
  }
  __syncthreads();
  __builtin_amdgcn_sched_barrier(0);  // no hoisting of loads above the spin
}

// ============================================================================
// Precompute: key_x_all = x @ Wk^T + bk ; val1_all = x @ Wv^T + bv
// Block 0 additionally zeroes the barrier counters (ws is poisoned).
// ============================================================================
__global__ void __launch_bounds__(256) keyval_kernel(
    const float* __restrict__ x, const float* __restrict__ Wk,
    const float* __restrict__ Wv, const float* __restrict__ bk,
    const float* __restrict__ bv, float* __restrict__ wsf) {
  __shared__ float Xs[64][33];
  __shared__ float Ws[64][33];
  int bid = blockIdx.x, tid = threadIdx.x;
  if (bid == 0) {
    for (int i = tid; i < BAR_WORDS; i += 256)
      reinterpret_cast<unsigned*>(wsf + BAR_OFF)[i] = 0u;
  }
  int m = bid / 96, r = bid % 96;
  int tt = r / 12, ot = r % 12;
  const float* xb = x + ((size_t)m * T_ + tt * 64) * D_;
  const float* wb; const float* bias; float* dst; int ld;
  if (ot < 4) {
    wb = Wk + (size_t)m * QK_ * D_ + (size_t)(ot * 64) * D_;
    bias = bk + m * QK_ + ot * 64;
    dst = wsf + KEY_OFF + ((size_t)m * T_ + tt * 64) * QK_ + ot * 64;
    ld = QK_;
  } else {
    wb = Wv + (size_t)m * D_ * D_ + (size_t)((ot - 4) * 64) * D_;
    bias = bv + m * D_ + (ot - 4) * 64;
    dst = wsf + VAL_OFF + ((size_t)m * T_ + tt * 64) * D_ + (ot - 4) * 64;
    ld = D_;
  }
  int lr = tid >> 2, lc = (tid & 3) * 8;
  int tx = tid & 15, ty = tid >> 4;
  float acc[4][4] = {};
  for (int k0 = 0; k0 < D_; k0 += 32) {
    float tmp[8];
    load8f(xb + (size_t)lr * D_ + k0 + lc, tmp);
#pragma unroll
    for (int i = 0; i < 8; ++i) Xs[lr][lc + i] = tmp[i];
    load8f(wb + (size_t)lr * D_ + k0 + lc, tmp);
#pragma unroll
    for (int i = 0; i < 8; ++i) Ws[lr][lc + i] = tmp[i];
    __syncthreads();
#pragma unroll
    for (int kk = 0; kk < 32; ++kk) {
      float xa[4], wv4[4];
#pragma unroll
      for (int a = 0; a < 4; ++a) xa[a] = Xs[ty * 4 + a][kk];
#pragma unroll
      for (int b = 0; b < 4; ++b) wv4[b] = Ws[tx * 4 + b][kk];
#pragma unroll
      for (int a = 0; a < 4; ++a)
#pragma unroll
        for (int b = 0; b < 4; ++b) acc[a][b] += xa[a] * wv4[b];
    }
    __syncthreads();
  }
#pragma unroll
  for (int b = 0; b < 4; ++b) {
    float bias_v = bias[tx * 4 + b];
#pragma unroll
    for (int a = 0; a < 4; ++a)
      dst[(size_t)(ty * 4 + a) * ld + tx * 4 + b] = acc[a][b] + bias_v;
  }
}

// ============================================================================
// Main sequential kernel. 256 WGs x 1024 threads. WG = (row m = wg>>4, g = wg&15).
// Persistent VGPR weights; fence-free barriers; mutable state via sc-bypass.
// ============================================================================
__global__ void __launch_bounds__(1024, 4) rim_main(
    const float* __restrict__ Wq, const float* __restrict__ bq,
    const float* __restrict__ bk, const float* __restrict__ bv,
    const float* __restrict__ Wih, const float* __restrict__ bih,
    const float* __restrict__ Whh, const float* __restrict__ bhh,
    const float* __restrict__ Wqg, const float* __restrict__ Wkg,
    const float* __restrict__ Wvg,
    float* __restrict__ wsf, float* __restrict__ out0, float* __restrict__ out1) {
  const int wg = blockIdx.x, tid = threadIdx.x;
  const int lane = tid & 63, wv = tid >> 6;
  const int m = wg >> 4, g = wg & 15;
  const int h32 = tid >> 5, oi = tid & 31;

  float* keyA = wsf + KEY_OFF;
  float* valA = wsf + VAL_OFF;
  float* hB  = wsf + H_OFF;
  float* cB  = wsf + C_OFF;
  float* thB = wsf + TH_OFF;
  float* k2B = wsf + K2_OFF;
  float* v2B = wsf + V2_OFF;
  float* q2B = wsf + Q2_OFF;
  float* l0B = wsf + L0_OFF;
  float* l1B = wsf + L1_OFF;

  __shared__ float s_newh[4][512];   // 8 KB
  __shared__ float s_dv[512];        // 2 KB
  __shared__ float s_pdk[16][32];    // 2 KB
  __shared__ float s_pdv[16][32];    // 2 KB
  __shared__ float s_pdq[16][32];    // 2 KB
  __shared__ float s_l0[256];        // 1 KB
  __shared__ float s_l1[256];        // 1 KB
  __shared__ float s_small[64];
  __shared__ float s_w2[64];
  __shared__ float s_redA[16];
  __shared__ float s_redB[16];
  __shared__ float s_gv[4][8];

  // ---- persistent register weights (loaded once, normal cached path) ----
  float wqr[8], wkr[16], wvr[16];
  load8f(Wq + ((size_t)m * QK_ + g * 16 + wv) * H_ + lane * 8, wqr);
  {
    const size_t wo = ((size_t)m * H_ + h32 * 16) * H_ + g * 32 + oi;
#pragma unroll
    for (int i = 0; i < 16; ++i) wkr[i] = Wkg[wo + (size_t)i * H_];
#pragma unroll
    for (int i = 0; i < 16; ++i) wvr[i] = Wvg[wo + (size_t)i * H_];
  }
  const float qb = bq[m * QK_ + g * 16 + wv];
  const float kb = bk[m * QK_ + g * 16 + wv];

  unsigned bno = 0;  // barrier index (uniform across grid)

  // ws is poisoned each call: zero-init state (bypass stores)
  if (g == 0 && tid < 512) {
    stf(hB + m * 512 + tid, 0.f);
    stf(cB + m * 512 + tid, 0.f);
  }
  gbar(wsf, ++bno);

  int p0 = 0, p1 = 0, p2 = 0, p3 = 0;  // active rows of step t-1
  int r0 = 0, r1 = 0, r2 = 0, r3 = 0;  // active rows of step t

  for (int t = 0; t <= T_; ++t) {
    int slot = -1;
    // ================= Phase A: epilogue of step t-1 =================
    if (t > 0) {
      slot = (m == p0) ? 0 : (m == p1) ? 1 : (m == p2) ? 2 : (m == p3) ? 3 : -1;
      if (slot >= 0) {
        if (tid < 512) {  // scores q2·k2
          int pr = tid >> 3, part = tid & 7;
          int s_ = pr >> 4, j_ = pr & 15;
          const float* q4 = q2B + s_ * 512 + part * 64;
          const float* k4 = k2B + j_ * 512 + part * 64;
          float acc = 0.f;
#pragma unroll
          for (int i = 0; i < 16; ++i) {
            float2 a0 = ldf2(q4 + i * 4), a1 = ldf2(q4 + i * 4 + 2);
            float2 b0 = ldf2(k4 + i * 4), b1 = ldf2(k4 + i * 4 + 2);
            acc += a0.x * b0.x + a0.y * b0.y + a1.x * b1.x + a1.y * b1.y;
          }
          acc += __shfl_xor(acc, 1);
          acc += __shfl_xor(acc, 2);
          acc += __shfl_xor(acc, 4);
          if (part == 0) s_small[pr] = acc;
        }
        __syncthreads();
        if (tid < 4) {  // row softmax (max-subtract)
          float mx = -1e30f;
          for (int j = 0; j < 16; ++j) mx = fmaxf(mx, s_small[tid * 16 + j]);
          float sm = 0.f;
          for (int j = 0; j < 16; ++j) {
            float e = expf(s_small[tid * 16 + j] - mx);
            s_w2[tid * 16 + j] = e; sm += e;
          }
          float inv = 1.f / sm;
          for (int j = 0; j < 16; ++j) s_w2[tid * 16 + j] *= inv;
        }
        __syncthreads();
        {  // inter + new_h
          int s_ = tid >> 8, o0 = (tid & 255) * 2;
          float ax = 0.f, ay = 0.f;
#pragma unroll
          for (int j = 0; j < 16; ++j) {
            float w = s_w2[s_ * 16 + j];
            float2 v = ldf2(v2B + j * 512 + o0);
            ax += w * v.x; ay += w * v.y;
          }
          int myrow = s_ == 0 ? p0 : s_ == 1 ? p1 : s_ == 2 ? p2 : p3;
          float2 th = ldf2(thB + (size_t)myrow * 512 + o0);
          s_newh[s_][o0] = ax + th.x;
          s_newh[s_][o0 + 1] = ay + th.y;
        }
        __syncthreads();
      }
      if (g == 0 && tid < 512) {  // out[t-1] all rows; h update prev-active
        float v = (slot >= 0) ? s_newh[slot][tid] : ldf(hB + m * 512 + tid);
        out0[(size_t)(t - 1) * (M_ * H_) + m * 512 + tid] = v;  // plain store
        if (slot >= 0) stf(hB + m * 512 + tid, v);
      }
    }
    if (t == T_) break;

    // --- A1: q = h@Wq^T + bq (register weights), logit partials ---
    {
      float kv = keyA[((size_t)m * T_ + t) * QK_ + g * 16 + wv];  // cached
      float hreg[8];
      if (slot >= 0) {
#pragma unroll
        for (int i = 0; i < 8; ++i) hreg[i] = s_newh[slot][lane * 8 + i];
      } else {
        ld8f_cg(hB + m * 512 + lane * 8, hreg);
      }
      float acc = 0.f;
#pragma unroll
      for (int i = 0; i < 8; ++i) acc += hreg[i] * wqr[i];
      acc = waveReduce(acc);
      if (lane == 0) {
        float q = acc + qb;
        s_redA[wv] = q * kv;
        s_redB[wv] = q * kb;
      }
      __syncthreads();
      if (tid == 0) {  // deterministic fixed-order partial
        float a = 0.f, b = 0.f;
        for (int w = 0; w < 16; ++w) { a += s_redA[w]; b += s_redB[w]; }
        stf(l1B + m * 16 + g, a);
        stf(l0B + m * 16 + g, b);
      }
    }
    gbar(wsf, ++bno);

    // ================= Phase C =================
    if (tid < 256) {  // parallel bypass-prefetch of all logit partials
      s_l0[tid] = ldf(l0B + tid);
      s_l1[tid] = ldf(l1B + tid);
    }
    __syncthreads();
    if (tid < 16) {
      float l0 = 0.f, l1 = 0.f;
      for (int i = 0; i < 16; ++i) { l0 += s_l0[tid * 16 + i]; l1 += s_l1[tid * 16 + i]; }
      l0 *= SCALE_; l1 *= SCALE_;
      float mx = fmaxf(l0, l1);
      float e0 = expf(l0 - mx), e1 = expf(l1 - mx);
      float inv = 1.f / (e0 + e1);
      s_small[tid] = e0 * inv;        // att0
      s_small[16 + tid] = e1 * inv;   // att1
    }
    __syncthreads();
    {  // top_k(-att0, 4): 4 smallest att0, ties -> smaller index
      unsigned chosen = 0;
      int rr[4];
#pragma unroll
      for (int s = 0; s < 4; ++s) {
        float best = -2.f; int bm = 0;
        for (int mm = 0; mm < 16; ++mm) {
          if (chosen & (1u << mm)) continue;
          float v = -s_small[mm];
          if (v > best) { best = v; bm = mm; }
        }
        rr[s] = bm; chosen |= 1u << bm;
      }
      r0 = rr[0]; r1 = rr[1]; r2 = rr[2]; r3 = rr[3];
    }
    if (wg == 0 && tid < 4) {
      int rowv = tid == 0 ? r0 : tid == 1 ? r1 : tid == 2 ? r2 : r3;
      out1[(size_t)t * 4 + tid] = (float)rowv;  // plain store
    }
    // --- C1: gates + LSTM cell. WG=(slot, j-chunk of 8); wave = 2 gates. ---
    {
      int slot_c = wg >> 6, jc = wg & 63, j0 = jc * 8;
      int mA = slot_c == 0 ? r0 : slot_c == 1 ? r1 : slot_c == 2 ? r2 : r3;
      float a0v = s_small[mA], a1v = s_small[16 + mA];
      float bvr[8], vlr[8], hr[8];
      load8f(bv + mA * D_ + lane * 8, bvr);                       // cached
      load8f(valA + ((size_t)mA * T_ + t) * D_ + lane * 8, vlr);  // cached
      ld8f_cg(hB + mA * 512 + lane * 8, hr);                      // bypass
      float selr[8];
#pragma unroll
      for (int i = 0; i < 8; ++i) selr[i] = a0v * bvr[i] + a1v * vlr[i];
#pragma unroll
      for (int u = 0; u < 2; ++u) {
        int gl = wv * 2 + u;            // 0..31
        int type = gl >> 3, jj = gl & 7;
        int gidx = type * 512 + j0 + jj;
        float wi[8], wh[8];
        load8f(Wih + ((size_t)mA * G4_ + gidx) * D_ + lane * 8, wi);  // cached
        load8f(Whh + ((size_t)mA * G4_ + gidx) * H_ + lane * 8, wh);  // cached
        float acc = 0.f;
#pragma unroll
        for (int k = 0; k < 8; ++k) acc += selr[k] * wi[k] + hr[k] * wh[k];
        acc = waveReduce(acc);
        if (lane == 0)
          s_gv[type][jj] = acc + bih[mA * G4_ + gidx] + bhh[mA * G4_ + gidx];
      }
      __syncthreads();
      if (tid < 8) {
        float gi = s_gv[0][tid], gf = s_gv[1][tid], gg = s_gv[2][tid], go = s_gv[3][tid];
        int j = j0 + tid;
        float cold = ldf(cB + mA * 512 + j);
        float cn = sigm(gf) * cold + sigm(gi) * tanhf(gg);
        float hn = sigm(go) * tanhf(cn);
        stf(cB + mA * 512 + j, cn);     // new_c (active rows)
        stf(thB + mA * 512 + j, hn);    // temp_h (active rows)
      }
    }
    gbar(wsf, ++bno);

    // ================= Phase D: k2/v2 (+q2) from persistent registers ======
    {
      unsigned amask = (1u << r0) | (1u << r1) | (1u << r2) | (1u << r3);
      unsigned pmask = (1u << p0) | (1u << p1) | (1u << p2) | (1u << p3);
      bool act = (amask >> m) & 1;
      bool prevact = (t > 0) && ((pmask >> m) & 1);
      bool dirty = act || prevact || (t == 0);
      if (dirty) {
        const float* src = act ? thB + m * 512 : hB + m * 512;
        if (tid < 512) s_dv[tid] = ldf(src + tid);
        float wq2[16];
        int qslot = -1;
        if (act) {  // stream Wqg slice for active rows (cached path)
          qslot = (m == r0) ? 0 : (m == r1) ? 1 : (m == r2) ? 2 : 3;
          const size_t wo = ((size_t)m * H_ + h32 * 16) * H_ + g * 32 + oi;
#pragma unroll
          for (int i = 0; i < 16; ++i) wq2[i] = Wqg[wo + (size_t)i * H_];
        }
        __syncthreads();
        float pk = 0.f, pv = 0.f, pq = 0.f;
#pragma unroll
        for (int i = 0; i < 16; ++i) {
          float s = s_dv[h32 * 16 + i];
          pk += s * wkr[i];
          pv += s * wvr[i];
        }
        if (act) {
#pragma unroll
          for (int i = 0; i < 16; ++i) pq += s_dv[h32 * 16 + i] * wq2[i];
        }
        pk += __shfl_xor(pk, 32);
        pv += __shfl_xor(pv, 32);
        pq += __shfl_xor(pq, 32);
        if (lane < 32) {
          s_pdk[wv][lane] = pk;
          s_pdv[wv][lane] = pv;
          s_pdq[wv][lane] = pq;
        }
        __syncthreads();
        if (tid < 32) {
          float a = 0.f, b = 0.f, c = 0.f;
          for (int w = 0; w < 16; ++w) {  // fixed order
            a += s_pdk[w][tid]; b += s_pdv[w][tid]; c += s_pdq[w][tid];
          }
          stf(k2B + m * 512 + g * 32 + tid, a);
          stf(v2B + m * 512 + g * 32 + tid, b);
          if (act) stf(q2B + qslot * 512 + g * 32 + tid, c);
        }
      }
      // new_c = m*c_new: zero c when a row just went inactive
      if (!act && prevact && g == 0 && tid < 512) stf(cB + m * 512 + tid, 0.f);
    }
    p0 = r0; p1 = r1; p2 = r2; p3 = r3;
    gbar(wsf, ++bno);
  }
}

// ============================================================================
extern "C" void kernel_launch(void* const* d_in, const int* in_sizes, int n_in,
                              void* d_out, int out_size, void* d_ws, size_t ws_size,
                              hipStream_t stream) {
  const float* x   = (const float*)d_in[0];
  const float* Wq  = (const float*)d_in[1];
  const float* bq  = (const float*)d_in[2];
  const float* Wk  = (const float*)d_in[3];
  const float* bk  = (const float*)d_in[4];
  const float* Wv  = (const float*)d_in[5];
  const float* bv  = (const float*)d_in[6];
  const float* Wih = (const float*)d_in[7];
  const float* bih = (const float*)d_in[8];
  const float* Whh = (const float*)d_in[9];
  const float* bhh = (const float*)d_in[10];
  const float* Wqg = (const float*)d_in[11];
  const float* Wkg = (const float*)d_in[12];
  const float* Wvg = (const float*)d_in[13];
  float* wsf = (float*)d_ws;
  float* out0 = (float*)d_out;
  float* out1 = out0 + (size_t)T_ * M_ * H_;
  (void)in_sizes; (void)n_in; (void)out_size; (void)ws_size;

  hipLaunchKernelGGL(keyval_kernel, dim3(1536), dim3(256), 0, stream,
                     x, Wk, Wv, bk, bv, wsf);

  void* kargs[] = {(void*)&Wq, (void*)&bq, (void*)&bk, (void*)&bv,
                   (void*)&Wih, (void*)&bih, (void*)&Whh, (void*)&bhh,
                   (void*)&Wqg, (void*)&Wkg, (void*)&Wvg,
                   (void*)&wsf, (void*)&out0, (void*)&out1};
  hipLaunchCooperativeKernel((void*)rim_main, dim3(256), dim3(1024), kargs, 0,
                             stream);
}